// Round 6
// baseline (246.488 us; speedup 1.0000x reference)
//
#include <hip/hip_runtime.h>

// out[b,s] = cumsum_s( softplus(beta * c[b,s]) / beta ), fp32, B=4096, S=8192.
//
// R7 design: TWO-PASS DECOUPLED SCAN (chunk sums in d_ws, then apply).
//   Post-mortem R2-R6: five structures, all 2.4-2.55 TB/s, all pipes <35%,
//   while fillBuffer streams 6.7 TB/s in the same trace. Invariant: the
//   serial scan topology embedded in the streaming loop chops every wave's
//   memory stream (dependent shuffle chains / load-use waits; VGPR counts
//   prove the compiler never held a deep pipeline). Fix: separate concerns.
//   - K1: 32768 independent waves, each reduces one 1024-elem chunk:
//     4 coalesced f4 loads -> softplus -> lane sum -> 6-shuffle butterfly ->
//     1 scalar store to ws[chunk]. PURE READ STREAM, short critical path,
//     8192-block queue (32 blocks/CU deep) -> memory pipe stays full.
//   - K2: per wave, chunk prefix = masked sum of its row's 8 chunk sums
//     (wave-uniform cached loads, no shuffles), then load chunk, softplus,
//     in-f4 scan + 4 independent 6-step wave scans, add offsets, store.
//     Same per-chunk scan cost as R4, but 128 queued waves/CU hide it.
//   - Input read twice, but K2's re-read follows K1's population of the
//     256MB L3 with the 134MB input -> mostly L3 hits. softplus computed
//     twice: VALU was 25% busy, it's free.
//   - Diagnostic: if K1 (pure read, zero serial topology) also lands at
//     2.4 TB/s, the read path IS the platform ceiling -> roofline proven.
//   - ws usage: 32768 floats = 128 KB in d_ws.

#define ROW_S   8192
#define CHUNK   1024                  // elems per wave-chunk
#define NCH     (ROW_S / CHUNK)       // 8 chunks per row
#define WPB     4                     // waves per block
#define BLOCK_T (WPB * 64)

typedef float f32x4 __attribute__((ext_vector_type(4)));

__device__ __forceinline__ float softplus_step(float c, float beta, float inv_beta) {
    float tb = beta * c;
    float a  = fabsf(tb);
    float e  = __expf(-a);             // in (0,1], no overflow
    float l  = __logf(1.0f + e);       // log1p(exp(-|t|))
    return (fmaxf(tb, 0.0f) + l) * inv_beta;
}

// ---- K1: per-chunk softplus sums -> ws[chunk] ----
__global__ __launch_bounds__(BLOCK_T) void chunk_sum_kernel(
    const float* __restrict__ c,
    const float* __restrict__ beta_p,
    float* __restrict__ sums,
    int nchunks)
{
    const int lane = threadIdx.x & 63;
    const int wave = threadIdx.x >> 6;
    const int gid  = blockIdx.x * WPB + wave;
    if (gid >= nchunks) return;                     // wave-uniform

    const float beta     = beta_p[0];
    const float inv_beta = 1.0f / beta;
    const f32x4* __restrict__ in4 = (const f32x4*)c + (size_t)gid * (CHUNK / 4);

    f32x4 v[4];
    #pragma unroll
    for (int j = 0; j < 4; ++j)
        v[j] = in4[j * 64 + lane];                  // coalesced 1KB/instr

    float s = 0.0f;
    #pragma unroll
    for (int j = 0; j < 4; ++j) {
        s += softplus_step(v[j].x, beta, inv_beta);
        s += softplus_step(v[j].y, beta, inv_beta);
        s += softplus_step(v[j].z, beta, inv_beta);
        s += softplus_step(v[j].w, beta, inv_beta);
    }

    #pragma unroll
    for (int d = 1; d < 64; d <<= 1)
        s += __shfl_xor(s, d, 64);                  // butterfly: all lanes get total

    if (lane == 0) sums[gid] = s;
}

// ---- K2: chunk prefix + in-chunk scan -> out ----
__global__ __launch_bounds__(BLOCK_T) void scan_apply_kernel(
    const float* __restrict__ c,
    const float* __restrict__ beta_p,
    const float* __restrict__ sums,
    float* __restrict__ out,
    int nchunks)
{
    const int lane = threadIdx.x & 63;
    const int wave = threadIdx.x >> 6;
    const int gid  = blockIdx.x * WPB + wave;
    if (gid >= nchunks) return;                     // wave-uniform

    const int jch     = gid & (NCH - 1);            // chunk index within row
    const int rowbase = gid & ~(NCH - 1);           // row's first chunk id

    const float beta     = beta_p[0];
    const float inv_beta = 1.0f / beta;

    // chunk prefix: masked sum of this row's chunk sums (wave-uniform loads,
    // 32B/row, heavily cached; jch is wave-uniform so no divergence)
    float pre0 = 0.0f;
    #pragma unroll
    for (int k = 0; k < NCH; ++k) {
        float w = sums[rowbase + k];
        if (k < jch) pre0 += w;
    }

    const f32x4* __restrict__ in4  = (const f32x4*)c   + (size_t)gid * (CHUNK / 4);
    f32x4*       __restrict__ out4 = (f32x4*)out       + (size_t)gid * (CHUNK / 4);

    f32x4 v[4];
    #pragma unroll
    for (int j = 0; j < 4; ++j)
        v[j] = in4[j * 64 + lane];                  // mostly L3-hit re-read

    // softplus + in-f4 inclusive scan
    f32x4 r[4];
    float s[4];
    #pragma unroll
    for (int j = 0; j < 4; ++j) {
        float a = softplus_step(v[j].x, beta, inv_beta);
        float b = softplus_step(v[j].y, beta, inv_beta);
        float d = softplus_step(v[j].z, beta, inv_beta);
        float e = softplus_step(v[j].w, beta, inv_beta);
        r[j].x = a;
        r[j].y = a + b;
        r[j].z = r[j].y + d;
        r[j].w = r[j].z + e;
        s[j]   = r[j].w;
    }

    // 4 independent wave-inclusive shuffle scans of chunk-group sums
    float xs[4], G[4];
    #pragma unroll
    for (int j = 0; j < 4; ++j) {
        float x = s[j];
        #pragma unroll
        for (int d = 1; d < 64; d <<= 1) {
            float y = __shfl_up(x, d, 64);
            if (lane >= d) x += y;
        }
        xs[j] = x;
        G[j]  = __shfl(x, 63, 64);                  // group total
    }

    // combine + coalesced stores
    float pre = pre0;
    #pragma unroll
    for (int j = 0; j < 4; ++j) {
        const float off = pre + (xs[j] - s[j]);     // exclusive prefix for lane
        pre += G[j];
        f32x4 o;
        o.x = r[j].x + off;
        o.y = r[j].y + off;
        o.z = r[j].z + off;
        o.w = r[j].w + off;
        out4[j * 64 + lane] = o;
    }
}

extern "C" void kernel_launch(void* const* d_in, const int* in_sizes, int n_in,
                              void* d_out, int out_size, void* d_ws, size_t ws_size,
                              hipStream_t stream) {
    const float* c      = (const float*)d_in[0];
    const float* beta_p = (const float*)d_in[1];
    float*       out    = (float*)d_out;

    const int B       = in_sizes[0] / ROW_S;        // 4096 rows
    const int nchunks = B * NCH;                    // 32768 chunks
    const int grid    = (nchunks + WPB - 1) / WPB;  // 8192 blocks

    float* sums = (float*)d_ws;                     // 128 KB of workspace

    chunk_sum_kernel<<<dim3(grid), dim3(BLOCK_T), 0, stream>>>(
        c, beta_p, sums, nchunks);
    scan_apply_kernel<<<dim3(grid), dim3(BLOCK_T), 0, stream>>>(
        c, beta_p, sums, out, nchunks);
}